// Round 7
// baseline (181.535 us; speedup 1.0000x reference)
//
#include <hip/hip_runtime.h>

// Net: x[B,2] -> fc1(2->9)+ELU -> 19 x (9->9)+ELU -> fc21(9->2) -> log_softmax
// B = 2097152. Round 7: round-6 structure (16x16x32 MFMA, relu/exp K-split,
// 4-way tile ILP, wave-batched softmax) with two changes:
//  (1) __launch_bounds__(256,2): VGPR cap 256 so all 21 A-fragments (84 VGPRs)
//      stay register-resident -> no VMEM reloads inside the layer chain.
//  (2) f32 activation epilogue with guaranteed single-instruction lowering:
//      3x v_max_f32, 3x v_min_f32, 3x v_exp_f32, 4x v_cvt_pkrtz, 1x v_or
//      (round 6's f16 path emitted hidden half-insert/pack ops).
//
// MFMA 16x16x32 f16 layouts:
//   C/D: lane L holds rows (L>>4)*4+reg        of col (L&15)   [4 f32]
//   B:   lane L holds k  = (L>>4)*8+j (j=0..7) of col (L&15)   [8 f16]
// Slot map (g=lane>>4): j=0..2 relu slots (k=8g+j), j=4..6 e2m slots
// (k=8g+4..6, g<3), k=24 (g=3,j=0) bias slot; j=3,7 and g=3 extras are dead
// (zero A columns), so garbage-free finite values there are harmless.
// Neurons permuted to rows {0,1,2,4,5,6,8,9,10} (p(i)=i+i/3) so D reg 3 is
// always +0.0 -> only 3 exps/lane/layer; rows 12..15 zero -> bias OR injects
// exactly 1.0h at g3 lo-half of reg 0.
//
// ELU identity: ELU(z) = relu(z) + exp2(min(L*z,0)) - 1 (L=log2e); scales and
// the -1 are folded into the next layer's weights/bias in build_frags.

typedef _Float16 half8 __attribute__((ext_vector_type(8)));
typedef float float4v __attribute__((ext_vector_type(4)));
typedef unsigned int uint4v __attribute__((ext_vector_type(4)));

constexpr int H   = 9;
constexpr int NL  = 21;    // fc1 + 19 mid + fc21
constexpr int TPW = 8;     // batch tiles (of 16 rows) per wave
constexpr int BLK = 256;

__global__ void build_frags(const float* __restrict__ W1, const float* __restrict__ b1,
                            const float* __restrict__ Wmid, const float* __restrict__ bmid,
                            const float* __restrict__ W21, const float* __restrict__ b21,
                            _Float16* __restrict__ ws) {
    const float L   = 1.4426950408889634f;   // log2(e)
    const float LN2 = 0.6931471805599453f;
    int l    = blockIdx.x;      // 0..20
    int lane = threadIdx.x;     // 0..63
    int row  = lane & 15;       // A row
    int g    = lane >> 4;       // k group
    bool orow = ((row & 3) != 3) && (row < 12);   // rows {0,1,2,4,5,6,8,9,10}
    int  o    = row - (row >> 2);                 // neuron index at this row
    for (int j = 0; j < 8; ++j) {
        int k = g * 8 + j;
        float v = 0.0f;
        if (l == 0) {
            if (orow && k < 2)        v = L * W1[o * 2 + k];
            else if (orow && k == 24) v = L * b1[o];
        } else if (l <= 19) {
            const float* W = Wmid + (l - 1) * 81;
            const float* b = bmid + (l - 1) * 9;
            if (orow) {
                if (j < 3 && g < 3) {                    // relu slot
                    int r_in = g * 4 + j;
                    int i = r_in - (r_in >> 2);
                    v = W[o * 9 + i];
                } else if (j >= 4 && j < 7 && g < 3) {   // e2m slot
                    int r_in = g * 4 + (j - 4);
                    int i = r_in - (r_in >> 2);
                    v = L * W[o * 9 + i];
                } else if (k == 24) {                    // bias slot
                    float s = 0.0f;
                    for (int i = 0; i < H; ++i) s += W[o * 9 + i];
                    v = L * (b[o] - s);
                }
            }
        } else {  // l == 20: logits at rows 0,1
            if (row < 2) {
                if (j < 3 && g < 3) {
                    int r_in = g * 4 + j;
                    int i = r_in - (r_in >> 2);
                    v = LN2 * W21[row * 9 + i];
                } else if (j >= 4 && j < 7 && g < 3) {
                    int r_in = g * 4 + (j - 4);
                    int i = r_in - (r_in >> 2);
                    v = W21[row * 9 + i];
                } else if (k == 24) {
                    float s = 0.0f;
                    for (int i = 0; i < H; ++i) s += W21[row * 9 + i];
                    v = b21[row] - s;
                }
            }
        }
        ws[l * 512 + lane * 8 + j] = (_Float16)v;
    }
}

// d (4 f32, d[3]==+0) -> next-layer B fragment. All single-instruction ops:
// 3 max, 3 min, 3 exp(trans), 4 pkrtz, 1 or.
__device__ __forceinline__ half8 act_to_b(float4v d, unsigned bias_or) {
    float r0 = fmaxf(d[0], 0.f), r1 = fmaxf(d[1], 0.f), r2 = fmaxf(d[2], 0.f);
    float t0 = fminf(d[0], 0.f), t1 = fminf(d[1], 0.f), t2 = fminf(d[2], 0.f);
    float e0 = __builtin_amdgcn_exp2f(t0);
    float e1 = __builtin_amdgcn_exp2f(t1);
    float e2 = __builtin_amdgcn_exp2f(t2);
    uint4v u;
    u[0] = __builtin_bit_cast(unsigned, __builtin_amdgcn_cvt_pkrtz(r0, r1)) | bias_or;
    u[1] = __builtin_bit_cast(unsigned, __builtin_amdgcn_cvt_pkrtz(r2, 0.f));
    u[2] = __builtin_bit_cast(unsigned, __builtin_amdgcn_cvt_pkrtz(e0, e1));
    u[3] = __builtin_bit_cast(unsigned, __builtin_amdgcn_cvt_pkrtz(e2, 1.f));
    return __builtin_bit_cast(half8, u);
}

// layer-0 B: k=0,1 = x (group 0 only), k=24 = 1.0h, rest 0
__device__ __forceinline__ half8 x_to_b(float2 xv, unsigned g0_sel, unsigned bias_or) {
    unsigned ux = __builtin_bit_cast(unsigned, __builtin_amdgcn_cvt_pkrtz(xv.x, xv.y));
    uint4v u;
    u[0] = (ux & g0_sel) | bias_or;
    u[1] = 0u; u[2] = 0u; u[3] = 0u;
    return __builtin_bit_cast(half8, u);
}

__device__ __forceinline__ float bperm(int byte_idx, float v) {
    return __builtin_bit_cast(float,
        __builtin_amdgcn_ds_bpermute(byte_idx, __builtin_bit_cast(int, v)));
}

__global__ __launch_bounds__(BLK, 2) void mlp_mfma(const float* __restrict__ x,
                                                   const _Float16* __restrict__ ws,
                                                   float* __restrict__ out) {
    const int lane = threadIdx.x & 63;
    const int wave = (blockIdx.x * BLK + threadIdx.x) >> 6;
    const int grp  = lane >> 4;
    const int col  = lane & 15;

    // All 21 A fragments register-resident (84 VGPRs under the 256 cap).
    half8 A[NL];
    const half8* wsv = (const half8*)ws;
    #pragma unroll
    for (int l = 0; l < NL; ++l) A[l] = wsv[l * 64 + lane];

    const unsigned bias_or = (grp == 3) ? 0x00003C00u : 0u;  // 1.0h, lo half
    const unsigned g0_sel  = (grp == 0) ? 0xFFFFFFFFu : 0u;
    const float4v ZV = {0.f, 0.f, 0.f, 0.f};
    const float NLOG2E = -1.4426950408889634f;
    const float LN2f   = 0.6931471805599453f;

    #pragma unroll 1
    for (int t = 0; t < TPW; t += 4) {
        const int tile0 = wave * TPW + t;           // < 131072, 32-bit safe

        half8 bf[4];
        #pragma unroll
        for (int k = 0; k < 4; ++k) {
            float2 xv = ((const float2*)x)[((tile0 + k) << 4) + col];
            bf[k] = x_to_b(xv, g0_sel, bias_or);
        }

        float4v dd[4];
        #pragma unroll
        for (int l = 0; l < NL; ++l) {
            #pragma unroll
            for (int k = 0; k < 4; ++k)
                dd[k] = __builtin_amdgcn_mfma_f32_16x16x32_f16(A[l], bf[k], ZV, 0, 0, 0);
            if (l < NL - 1) {
                #pragma unroll
                for (int k = 0; k < 4; ++k)
                    bf[k] = act_to_b(dd[k], bias_or);
            }
        }

        // Wave-batched log-softmax: bpermute spreads tile k's logits (lanes
        // 0..15, regs 0,1) to lane 16k+m; one full-wave softplus lse and one
        // fully-coalesced 512B float2 store.
        const int bidx = col << 2;
        float a0 = bperm(bidx, dd[0][0]), a1 = bperm(bidx, dd[0][1]);
        float b0 = bperm(bidx, dd[1][0]), b1 = bperm(bidx, dd[1][1]);
        float c0 = bperm(bidx, dd[2][0]), c1 = bperm(bidx, dd[2][1]);
        float d0 = bperm(bidx, dd[3][0]), d1 = bperm(bidx, dd[3][1]);
        float l0 = (grp == 0) ? a0 : (grp == 1) ? b0 : (grp == 2) ? c0 : d0;
        float l1 = (grp == 0) ? a1 : (grp == 1) ? b1 : (grp == 2) ? c1 : d1;

        float mx  = fmaxf(l0, l1);
        float ad  = fabsf(l0 - l1);
        float e   = __builtin_amdgcn_exp2f(NLOG2E * ad);
        float lg  = __builtin_amdgcn_logf(1.0f + e);     // log2(1+e)
        float lse = fmaf(LN2f, lg, mx);
        ((float2*)out)[(tile0 << 4) + lane] = make_float2(l0 - lse, l1 - lse);
    }
}

extern "C" void kernel_launch(void* const* d_in, const int* in_sizes, int n_in,
                              void* d_out, int out_size, void* d_ws, size_t ws_size,
                              hipStream_t stream) {
    const float* x    = (const float*)d_in[0];
    const float* W1   = (const float*)d_in[1];
    const float* b1   = (const float*)d_in[2];
    const float* Wmid = (const float*)d_in[3];
    const float* bmid = (const float*)d_in[4];
    const float* W21  = (const float*)d_in[5];
    const float* b21  = (const float*)d_in[6];
    float* out = (float*)d_out;
    _Float16* ws = (_Float16*)d_ws;   // 21*512 halves = 21.5 KB

    build_frags<<<NL, 64, 0, stream>>>(W1, b1, Wmid, bmid, W21, b21, ws);

    const int nrows = in_sizes[0] / 2;           // 2097152
    const int tiles = nrows / 16;                // 131072
    const int waves = tiles / TPW;               // 16384
    const int blocks = waves * 64 / BLK;         // 4096
    mlp_mfma<<<blocks, BLK, 0, stream>>>(x, ws, out);
}

// Round 8
// 176.889 us; speedup vs baseline: 1.0263x; 1.0263x over previous
//
#include <hip/hip_runtime.h>

// Net: x[B,2] -> fc1(2->9)+ELU -> 19 x (9->9)+ELU -> fc21(9->2) -> log_softmax
// B = 2097152. Round 8: round-7 math, restructured for occupancy/stalls:
//  (1) BLK=64 single-wave blocks, __launch_bounds__(64,4): 16384 small blocks
//      pack CUs better than 4-wave blocks (Occ stuck at 39% for 3 rounds).
//  (2) All 8 x-loads hoisted to wave start (no mid-kernel VMEM dependency).
//  (3) relu path of the epilogue in packed f16 (pkrtz -> pk_max), 13 instr.
//
// MFMA 16x16x32 f16 layouts:
//   C/D: lane L holds rows (L>>4)*4+reg        of col (L&15)   [4 f32]
//   B:   lane L holds k  = (L>>4)*8+j (j=0..7) of col (L&15)   [8 f16]
// Slot map (g=lane>>4): j=0..2 relu slots (k=8g+j), j=4..6 e2m slots (g<3),
// k=24 (g=3,j=0) bias slot; j=3,7 + g=3 extras are dead (zero A columns).
// Neurons permuted to rows {0,1,2,4,5,6,8,9,10} (p(i)=i+i/3) so D reg 3 is
// always +0.0 -> 3 exps/lane/layer; rows 12..15 zero -> bias OR injects 1.0h.
//
// ELU identity: ELU(z) = relu(z) + exp2(min(L*z,0)) - 1 (L=log2e); scales and
// the -1 folded into next layer's weights/bias in build_frags.

typedef _Float16 half8 __attribute__((ext_vector_type(8)));
typedef _Float16 h2 __attribute__((ext_vector_type(2)));
typedef float float4v __attribute__((ext_vector_type(4)));
typedef unsigned int uint4v __attribute__((ext_vector_type(4)));

constexpr int H   = 9;
constexpr int NL  = 21;    // fc1 + 19 mid + fc21
constexpr int TPW = 8;     // batch tiles (of 16 rows) per wave
constexpr int BLK = 64;    // single-wave workgroups

__global__ void build_frags(const float* __restrict__ W1, const float* __restrict__ b1,
                            const float* __restrict__ Wmid, const float* __restrict__ bmid,
                            const float* __restrict__ W21, const float* __restrict__ b21,
                            _Float16* __restrict__ ws) {
    const float L   = 1.4426950408889634f;   // log2(e)
    const float LN2 = 0.6931471805599453f;
    int l    = blockIdx.x;      // 0..20
    int lane = threadIdx.x;     // 0..63
    int row  = lane & 15;       // A row
    int g    = lane >> 4;       // k group
    bool orow = ((row & 3) != 3) && (row < 12);   // rows {0,1,2,4,5,6,8,9,10}
    int  o    = row - (row >> 2);                 // neuron index at this row
    for (int j = 0; j < 8; ++j) {
        int k = g * 8 + j;
        float v = 0.0f;
        if (l == 0) {
            if (orow && k < 2)        v = L * W1[o * 2 + k];
            else if (orow && k == 24) v = L * b1[o];
        } else if (l <= 19) {
            const float* W = Wmid + (l - 1) * 81;
            const float* b = bmid + (l - 1) * 9;
            if (orow) {
                if (j < 3 && g < 3) {                    // relu slot
                    int r_in = g * 4 + j;
                    int i = r_in - (r_in >> 2);
                    v = W[o * 9 + i];
                } else if (j >= 4 && j < 7 && g < 3) {   // e2m slot
                    int r_in = g * 4 + (j - 4);
                    int i = r_in - (r_in >> 2);
                    v = L * W[o * 9 + i];
                } else if (k == 24) {                    // bias slot
                    float s = 0.0f;
                    for (int i = 0; i < H; ++i) s += W[o * 9 + i];
                    v = L * (b[o] - s);
                }
            }
        } else {  // l == 20: logits at rows 0,1
            if (row < 2) {
                if (j < 3 && g < 3) {
                    int r_in = g * 4 + j;
                    int i = r_in - (r_in >> 2);
                    v = LN2 * W21[row * 9 + i];
                } else if (j >= 4 && j < 7 && g < 3) {
                    int r_in = g * 4 + (j - 4);
                    int i = r_in - (r_in >> 2);
                    v = W21[row * 9 + i];
                } else if (k == 24) {
                    float s = 0.0f;
                    for (int i = 0; i < H; ++i) s += W21[row * 9 + i];
                    v = b21[row] - s;
                }
            }
        }
        ws[l * 512 + lane * 8 + j] = (_Float16)v;
    }
}

// d (4 f32, d[3]==+0) -> next-layer B fragment.
// 2 pkrtz + 2 pk_max + 3 min + 3 exp(trans) + 2 pkrtz + 1 or = 13 issue slots.
__device__ __forceinline__ half8 act_to_b(float4v d, unsigned bias_or) {
    const h2 Z = {(_Float16)0.f, (_Float16)0.f};
    h2 p01 = __builtin_bit_cast(h2, __builtin_amdgcn_cvt_pkrtz(d[0], d[1]));
    h2 p2x = __builtin_bit_cast(h2, __builtin_amdgcn_cvt_pkrtz(d[2], 0.f));
    h2 r01 = __builtin_elementwise_max(p01, Z);
    h2 r2x = __builtin_elementwise_max(p2x, Z);
    float t0 = fminf(d[0], 0.f);
    float t1 = fminf(d[1], 0.f);
    float t2 = fminf(d[2], 0.f);
    float e0 = __builtin_amdgcn_exp2f(t0);
    float e1 = __builtin_amdgcn_exp2f(t1);
    float e2 = __builtin_amdgcn_exp2f(t2);
    uint4v u;
    u[0] = __builtin_bit_cast(unsigned, r01) | bias_or;  // bias 1.0h @ g3 j0
    u[1] = __builtin_bit_cast(unsigned, r2x);
    u[2] = __builtin_bit_cast(unsigned, __builtin_amdgcn_cvt_pkrtz(e0, e1));
    u[3] = __builtin_bit_cast(unsigned, __builtin_amdgcn_cvt_pkrtz(e2, 1.f));
    return __builtin_bit_cast(half8, u);
}

// layer-0 B: k=0,1 = x (group 0 only), k=24 = 1.0h, rest 0
__device__ __forceinline__ half8 x_to_b(float2 xv, unsigned g0_sel, unsigned bias_or) {
    unsigned ux = __builtin_bit_cast(unsigned, __builtin_amdgcn_cvt_pkrtz(xv.x, xv.y));
    uint4v u;
    u[0] = (ux & g0_sel) | bias_or;
    u[1] = 0u; u[2] = 0u; u[3] = 0u;
    return __builtin_bit_cast(half8, u);
}

__device__ __forceinline__ float bperm(int byte_idx, float v) {
    return __builtin_bit_cast(float,
        __builtin_amdgcn_ds_bpermute(byte_idx, __builtin_bit_cast(int, v)));
}

// One 4-tile group: 21-layer MFMA chain + wave-batched log-softmax + store.
__device__ __forceinline__ void run_group(const half8* __restrict__ A,
                                          const float2* __restrict__ xv,  // [4]
                                          int gbase, int lane, int grp,
                                          unsigned g0_sel, unsigned bias_or,
                                          float* __restrict__ out) {
    const float4v ZV = {0.f, 0.f, 0.f, 0.f};
    const float NLOG2E = -1.4426950408889634f;
    const float LN2f   = 0.6931471805599453f;
    const int col = lane & 15;

    half8 bf[4];
    #pragma unroll
    for (int k = 0; k < 4; ++k) bf[k] = x_to_b(xv[k], g0_sel, bias_or);

    float4v dd[4];
    #pragma unroll
    for (int l = 0; l < NL; ++l) {
        #pragma unroll
        for (int k = 0; k < 4; ++k)
            dd[k] = __builtin_amdgcn_mfma_f32_16x16x32_f16(A[l], bf[k], ZV, 0, 0, 0);
        if (l < NL - 1) {
            #pragma unroll
            for (int k = 0; k < 4; ++k)
                bf[k] = act_to_b(dd[k], bias_or);
        }
    }

    // bpermute spreads tile k's logits (lanes 0..15, regs 0,1) to lane 16k+m;
    // one full-wave softplus lse and one fully-coalesced 512B float2 store.
    const int bidx = col << 2;
    float a0 = bperm(bidx, dd[0][0]), a1 = bperm(bidx, dd[0][1]);
    float b0 = bperm(bidx, dd[1][0]), b1 = bperm(bidx, dd[1][1]);
    float c0 = bperm(bidx, dd[2][0]), c1 = bperm(bidx, dd[2][1]);
    float d0 = bperm(bidx, dd[3][0]), d1 = bperm(bidx, dd[3][1]);
    float l0 = (grp == 0) ? a0 : (grp == 1) ? b0 : (grp == 2) ? c0 : d0;
    float l1 = (grp == 0) ? a1 : (grp == 1) ? b1 : (grp == 2) ? c1 : d1;

    float mx  = fmaxf(l0, l1);
    float ad  = fabsf(l0 - l1);
    float e   = __builtin_amdgcn_exp2f(NLOG2E * ad);
    float lg  = __builtin_amdgcn_logf(1.0f + e);     // log2(1+e)
    float lse = fmaf(LN2f, lg, mx);
    ((float2*)out)[(gbase << 4) + lane] = make_float2(l0 - lse, l1 - lse);
}

__global__ __launch_bounds__(BLK, 4) void mlp_mfma(const float* __restrict__ x,
                                                   const _Float16* __restrict__ ws,
                                                   float* __restrict__ out) {
    const int lane  = threadIdx.x;        // single wave per block
    const int grp   = lane >> 4;
    const int col   = lane & 15;
    const int tile0 = blockIdx.x * TPW;   // < 131072, 32-bit safe

    half8 A[NL];
    const half8* wsv = (const half8*)ws;
    #pragma unroll
    for (int l = 0; l < NL; ++l) A[l] = wsv[l * 64 + lane];

    // Hoist ALL x loads for both groups to wave start.
    float2 xv[TPW];
    #pragma unroll
    for (int k = 0; k < TPW; ++k)
        xv[k] = ((const float2*)x)[((tile0 + k) << 4) + col];

    const unsigned bias_or = (grp == 3) ? 0x00003C00u : 0u;  // 1.0h, lo half
    const unsigned g0_sel  = (grp == 0) ? 0xFFFFFFFFu : 0u;

    run_group(A, xv,     tile0,     lane, grp, g0_sel, bias_or, out);
    run_group(A, xv + 4, tile0 + 4, lane, grp, g0_sel, bias_or, out);
}

extern "C" void kernel_launch(void* const* d_in, const int* in_sizes, int n_in,
                              void* d_out, int out_size, void* d_ws, size_t ws_size,
                              hipStream_t stream) {
    const float* x    = (const float*)d_in[0];
    const float* W1   = (const float*)d_in[1];
    const float* b1   = (const float*)d_in[2];
    const float* Wmid = (const float*)d_in[3];
    const float* bmid = (const float*)d_in[4];
    const float* W21  = (const float*)d_in[5];
    const float* b21  = (const float*)d_in[6];
    float* out = (float*)d_out;
    _Float16* ws = (_Float16*)d_ws;   // 21*512 halves = 21.5 KB

    build_frags<<<NL, 64, 0, stream>>>(W1, b1, Wmid, bmid, W21, b21, ws);

    const int nrows = in_sizes[0] / 2;           // 2097152
    const int tiles = nrows / 16;                // 131072
    const int blocks = tiles / TPW;              // 16384 single-wave blocks
    mlp_mfma<<<blocks, BLK, 0, stream>>>(x, ws, out);
}

// Round 9
// 158.273 us; speedup vs baseline: 1.1470x; 1.1176x over previous
//
#include <hip/hip_runtime.h>

// Net: x[B,2] -> fc1(2->9)+ELU -> 19 x (9->9)+ELU -> fc21(9->2) -> log_softmax
// B = 2097152. Round 9: trans-pipe attack + 8-chain ILP.
//  (1) e-branch in f16: reuse relu-side pkrtz, pk_min_f16, v_exp_f16 x3
//      (2 packed via __builtin_elementwise_exp2 + 1 scalar), u[3] built by
//      OR with 1.0h constant. Probes whether f16 trans is faster than f32.
//  (2) Both 4-tile groups fused into ONE 8-chain layer loop (8 independent
//      MFMA->act dependency chains) to fill idle issue slots.
//
// MFMA 16x16x32 f16 layouts:
//   C/D: lane L holds rows (L>>4)*4+reg        of col (L&15)   [4 f32]
//   B:   lane L holds k  = (L>>4)*8+j (j=0..7) of col (L&15)   [8 f16]
// Slot map (g=lane>>4): u[0]=j0,1 relu(d0,d1); u[1]=j2,3 relu(d2),dead;
// u[2]=j4,5 e(d0),e(d1); u[3]=j6,7 e(d2),dead(=1.0h); k=24 (g3 j0) bias 1.0h.
// Neurons at rows {0,1,2,4,5,6,8,9,10} (p(i)=i+i/3) -> D reg 3 always +0.0;
// rows 12..15 zero -> bias OR injects exactly 1.0h (relu(+0)=+0).
//
// ELU identity: ELU(z) = relu(z) + exp2(min(L*z,0)) - 1 (L=log2e); scales and
// the -1 folded into next layer's weights/bias in build_frags.

typedef _Float16 half8 __attribute__((ext_vector_type(8)));
typedef _Float16 h2 __attribute__((ext_vector_type(2)));
typedef float float4v __attribute__((ext_vector_type(4)));
typedef unsigned int uint4v __attribute__((ext_vector_type(4)));

extern "C" __device__ _Float16 __ocml_exp2_f16(_Float16);

constexpr int H   = 9;
constexpr int NL  = 21;    // fc1 + 19 mid + fc21
constexpr int TPW = 8;     // batch tiles (of 16 rows) per wave = 8 chains
constexpr int BLK = 64;    // single-wave workgroups

__global__ void build_frags(const float* __restrict__ W1, const float* __restrict__ b1,
                            const float* __restrict__ Wmid, const float* __restrict__ bmid,
                            const float* __restrict__ W21, const float* __restrict__ b21,
                            _Float16* __restrict__ ws) {
    const float L   = 1.4426950408889634f;   // log2(e)
    const float LN2 = 0.6931471805599453f;
    int l    = blockIdx.x;      // 0..20
    int lane = threadIdx.x;     // 0..63
    int row  = lane & 15;       // A row
    int g    = lane >> 4;       // k group
    bool orow = ((row & 3) != 3) && (row < 12);   // rows {0,1,2,4,5,6,8,9,10}
    int  o    = row - (row >> 2);                 // neuron index at this row
    for (int j = 0; j < 8; ++j) {
        int k = g * 8 + j;
        float v = 0.0f;
        if (l == 0) {
            if (orow && k < 2)        v = L * W1[o * 2 + k];
            else if (orow && k == 24) v = L * b1[o];
        } else if (l <= 19) {
            const float* W = Wmid + (l - 1) * 81;
            const float* b = bmid + (l - 1) * 9;
            if (orow) {
                if (j < 3 && g < 3) {                    // relu slot
                    int r_in = g * 4 + j;
                    int i = r_in - (r_in >> 2);
                    v = W[o * 9 + i];
                } else if (j >= 4 && j < 7 && g < 3) {   // e2m slot
                    int r_in = g * 4 + (j - 4);
                    int i = r_in - (r_in >> 2);
                    v = L * W[o * 9 + i];
                } else if (k == 24) {                    // bias slot
                    float s = 0.0f;
                    for (int i = 0; i < H; ++i) s += W[o * 9 + i];
                    v = L * (b[o] - s);
                }
            }
        } else {  // l == 20: logits at rows 0,1
            if (row < 2) {
                if (j < 3 && g < 3) {
                    int r_in = g * 4 + j;
                    int i = r_in - (r_in >> 2);
                    v = LN2 * W21[row * 9 + i];
                } else if (j >= 4 && j < 7 && g < 3) {
                    int r_in = g * 4 + (j - 4);
                    int i = r_in - (r_in >> 2);
                    v = W21[row * 9 + i];
                } else if (k == 24) {
                    float s = 0.0f;
                    for (int i = 0; i < H; ++i) s += W21[row * 9 + i];
                    v = b21[row] - s;
                }
            }
        }
        ws[l * 512 + lane * 8 + j] = (_Float16)v;
    }
}

// d (4 f32, d[3]==+0) -> next-layer B fragment. f16 e-branch:
// 2 pkrtz + 2 pk_max + 2 pk_min + 3 v_exp_f16 + 2 or.
__device__ __forceinline__ half8 act_to_b(float4v d, unsigned bias_or) {
    const h2 Z = {(_Float16)0.f, (_Float16)0.f};
    h2 p01 = __builtin_bit_cast(h2, __builtin_amdgcn_cvt_pkrtz(d[0], d[1]));
    h2 p2x = __builtin_bit_cast(h2, __builtin_amdgcn_cvt_pkrtz(d[2], 0.f));
    h2 r01 = __builtin_elementwise_max(p01, Z);
    h2 r2x = __builtin_elementwise_max(p2x, Z);
    h2 t01 = __builtin_elementwise_min(p01, Z);
    h2 t2x = __builtin_elementwise_min(p2x, Z);
    h2 e01 = __builtin_elementwise_exp2(t01);      // 2x v_exp_f16
    _Float16 e2 = __ocml_exp2_f16(t2x[0]);         // 1x v_exp_f16
    uint4v u;
    u[0] = __builtin_bit_cast(unsigned, r01) | bias_or;  // bias 1.0h @ g3 j0
    u[1] = __builtin_bit_cast(unsigned, r2x);
    u[2] = __builtin_bit_cast(unsigned, e01);
    u[3] = 0x3C000000u |                                  // 1.0h in dead j7
           (unsigned)__builtin_bit_cast(unsigned short, e2);
    return __builtin_bit_cast(half8, u);
}

// layer-0 B: k=0,1 = x (group 0 only), k=24 = 1.0h, rest 0
__device__ __forceinline__ half8 x_to_b(float2 xv, unsigned g0_sel, unsigned bias_or) {
    unsigned ux = __builtin_bit_cast(unsigned, __builtin_amdgcn_cvt_pkrtz(xv.x, xv.y));
    uint4v u;
    u[0] = (ux & g0_sel) | bias_or;
    u[1] = 0u; u[2] = 0u; u[3] = 0u;
    return __builtin_bit_cast(half8, u);
}

__device__ __forceinline__ float bperm(int byte_idx, float v) {
    return __builtin_bit_cast(float,
        __builtin_amdgcn_ds_bpermute(byte_idx, __builtin_bit_cast(int, v)));
}

// Wave-batched log-softmax + store for 4 tiles (dd[0..3] -> tiles gbase..+3).
__device__ __forceinline__ void softmax4(const float4v* dd, int gbase,
                                         int lane, int grp,
                                         float* __restrict__ out) {
    const float NLOG2E = -1.4426950408889634f;
    const float LN2f   = 0.6931471805599453f;
    const int bidx = (lane & 15) << 2;
    float a0 = bperm(bidx, dd[0][0]), a1 = bperm(bidx, dd[0][1]);
    float b0 = bperm(bidx, dd[1][0]), b1 = bperm(bidx, dd[1][1]);
    float c0 = bperm(bidx, dd[2][0]), c1 = bperm(bidx, dd[2][1]);
    float d0 = bperm(bidx, dd[3][0]), d1 = bperm(bidx, dd[3][1]);
    float l0 = (grp == 0) ? a0 : (grp == 1) ? b0 : (grp == 2) ? c0 : d0;
    float l1 = (grp == 0) ? a1 : (grp == 1) ? b1 : (grp == 2) ? c1 : d1;
    float mx  = fmaxf(l0, l1);
    float ad  = fabsf(l0 - l1);
    float e   = __builtin_amdgcn_exp2f(NLOG2E * ad);
    float lg  = __builtin_amdgcn_logf(1.0f + e);     // log2(1+e)
    float lse = fmaf(LN2f, lg, mx);
    ((float2*)out)[(gbase << 4) + lane] = make_float2(l0 - lse, l1 - lse);
}

__global__ __launch_bounds__(BLK, 4) void mlp_mfma(const float* __restrict__ x,
                                                   const _Float16* __restrict__ ws,
                                                   float* __restrict__ out) {
    const int lane  = threadIdx.x;        // single wave per block
    const int grp   = lane >> 4;
    const int col   = lane & 15;
    const int tile0 = blockIdx.x * TPW;   // < 131072, 32-bit safe

    const half8* wsv = (const half8*)ws;
    const unsigned bias_or = (grp == 3) ? 0x00003C00u : 0u;  // 1.0h, lo half
    const unsigned g0_sel  = (grp == 0) ? 0xFFFFFFFFu : 0u;
    const float4v ZV = {0.f, 0.f, 0.f, 0.f};

    // Hoist all 8 x loads.
    float2 xv[TPW];
    #pragma unroll
    for (int k = 0; k < TPW; ++k)
        xv[k] = ((const float2*)x)[((tile0 + k) << 4) + col];

    half8 bf[TPW];
    #pragma unroll
    for (int k = 0; k < TPW; ++k) bf[k] = x_to_b(xv[k], g0_sel, bias_or);

    // 21-layer chain, 8 independent chains in flight.
    float4v dd[TPW];
    #pragma unroll
    for (int l = 0; l < NL; ++l) {
        half8 A = wsv[l * 64 + lane];
        #pragma unroll
        for (int k = 0; k < TPW; ++k)
            dd[k] = __builtin_amdgcn_mfma_f32_16x16x32_f16(A, bf[k], ZV, 0, 0, 0);
        if (l < NL - 1) {
            #pragma unroll
            for (int k = 0; k < TPW; ++k)
                bf[k] = act_to_b(dd[k], bias_or);
        }
    }

    softmax4(dd,     tile0,     lane, grp, out);
    softmax4(dd + 4, tile0 + 4, lane, grp, out);
}

extern "C" void kernel_launch(void* const* d_in, const int* in_sizes, int n_in,
                              void* d_out, int out_size, void* d_ws, size_t ws_size,
                              hipStream_t stream) {
    const float* x    = (const float*)d_in[0];
    const float* W1   = (const float*)d_in[1];
    const float* b1   = (const float*)d_in[2];
    const float* Wmid = (const float*)d_in[3];
    const float* bmid = (const float*)d_in[4];
    const float* W21  = (const float*)d_in[5];
    const float* b21  = (const float*)d_in[6];
    float* out = (float*)d_out;
    _Float16* ws = (_Float16*)d_ws;   // 21*512 halves = 21.5 KB

    build_frags<<<NL, 64, 0, stream>>>(W1, b1, Wmid, bmid, W21, b21, ws);

    const int nrows = in_sizes[0] / 2;           // 2097152
    const int tiles = nrows / 16;                // 131072
    const int blocks = tiles / TPW;              // 16384 single-wave blocks
    mlp_mfma<<<blocks, BLK, 0, stream>>>(x, ws, out);
}

// Round 10
// 155.951 us; speedup vs baseline: 1.1641x; 1.0149x over previous
//
#include <hip/hip_runtime.h>

// Net: x[B,2] -> fc1(2->9)+ELU -> 19 x (9->9)+ELU -> fc21(9->2) -> log_softmax
// B = 2097152. Round 10: round-9 math with
//  (1) TPW=16 (two 8-chain passes per wave): wave-startup HBM latency and
//      per-wave fixed costs amortized over 2x work; all 16 x-fragments
//      pre-packed into 1 VGPR each at wave start.
//  (2) bias via pkrtz constant: bias column moved 24 -> 27 (g3, j3 = hi half
//      of u[1]); u[1] = pk_max(pkrtz(d2, 1.0f), 0) carries [relu(d2), 1.0h].
//      Kills the u[0] OR: 10 VALU+trans insts per layer-tile.
//      (cols 3,11,19 = j3 for g<3 are zero A-columns, the 1.0h is harmless)
//
// MFMA 16x16x32 f16 layouts:
//   C/D: lane L holds rows (L>>4)*4+reg        of col (L&15)   [4 f32]
//   B:   lane L holds k  = (L>>4)*8+j (j=0..7) of col (L&15)   [8 f16]
// u[0]=j0,1 relu(d0,d1); u[1]=j2,3 [relu(d2), 1.0h]; u[2]=j4,5 e(d0),e(d1);
// u[3]=j6,7 [e(d2), 1.0h-dead].  Bias col 27 (g3 j3); e2m cols k=8g+4..6.
// Neurons at rows {0,1,2,4,5,6,8,9,10} (p(i)=i+i/3) -> D reg 3 always +0.0
// -> 3 exps/lane/layer; rows 12..15 zero.
//
// ELU identity: ELU(z) = relu(z) + exp2(min(L*z,0)) - 1 (L=log2e); scales and
// the -1 folded into next layer's weights/bias in build_frags.

typedef _Float16 half8 __attribute__((ext_vector_type(8)));
typedef _Float16 h2 __attribute__((ext_vector_type(2)));
typedef float float4v __attribute__((ext_vector_type(4)));
typedef unsigned int uint4v __attribute__((ext_vector_type(4)));

extern "C" __device__ _Float16 __ocml_exp2_f16(_Float16);

constexpr int H   = 9;
constexpr int NL  = 21;    // fc1 + 19 mid + fc21
constexpr int TPW = 16;    // batch tiles (of 16 rows) per wave, 2 passes of 8
constexpr int BLK = 64;    // single-wave workgroups

__global__ void build_frags(const float* __restrict__ W1, const float* __restrict__ b1,
                            const float* __restrict__ Wmid, const float* __restrict__ bmid,
                            const float* __restrict__ W21, const float* __restrict__ b21,
                            _Float16* __restrict__ ws) {
    const float L   = 1.4426950408889634f;   // log2(e)
    const float LN2 = 0.6931471805599453f;
    int l    = blockIdx.x;      // 0..20
    int lane = threadIdx.x;     // 0..63
    int row  = lane & 15;       // A row
    int g    = lane >> 4;       // k group
    bool orow = ((row & 3) != 3) && (row < 12);   // rows {0,1,2,4,5,6,8,9,10}
    int  o    = row - (row >> 2);                 // neuron index at this row
    for (int j = 0; j < 8; ++j) {
        int k = g * 8 + j;
        float v = 0.0f;
        if (l == 0) {
            if (orow && k < 2)        v = L * W1[o * 2 + k];
            else if (orow && k == 27) v = L * b1[o];
        } else if (l <= 19) {
            const float* W = Wmid + (l - 1) * 81;
            const float* b = bmid + (l - 1) * 9;
            if (orow) {
                if (j < 3 && g < 3) {                    // relu slot
                    int r_in = g * 4 + j;
                    int i = r_in - (r_in >> 2);
                    v = W[o * 9 + i];
                } else if (j >= 4 && j < 7 && g < 3) {   // e2m slot
                    int r_in = g * 4 + (j - 4);
                    int i = r_in - (r_in >> 2);
                    v = L * W[o * 9 + i];
                } else if (k == 27) {                    // bias slot (g3 j3)
                    float s = 0.0f;
                    for (int i = 0; i < H; ++i) s += W[o * 9 + i];
                    v = L * (b[o] - s);
                }
            }
        } else {  // l == 20: logits at rows 0,1
            if (row < 2) {
                if (j < 3 && g < 3) {
                    int r_in = g * 4 + j;
                    int i = r_in - (r_in >> 2);
                    v = LN2 * W21[row * 9 + i];
                } else if (j >= 4 && j < 7 && g < 3) {
                    int r_in = g * 4 + (j - 4);
                    int i = r_in - (r_in >> 2);
                    v = W21[row * 9 + i];
                } else if (k == 27) {
                    float s = 0.0f;
                    for (int i = 0; i < H; ++i) s += W21[row * 9 + i];
                    v = b21[row] - s;
                }
            }
        }
        ws[l * 512 + lane * 8 + j] = (_Float16)v;
    }
}

// d (4 f32, d[3]==+0) -> next-layer B fragment.
// 2 pkrtz + 2 pk_max + 2 pk_min + 3 v_exp_f16 + 1 or = 10 issue slots.
__device__ __forceinline__ half8 act_to_b(float4v d) {
    const h2 Z = {(_Float16)0.f, (_Float16)0.f};
    h2 p01 = __builtin_bit_cast(h2, __builtin_amdgcn_cvt_pkrtz(d[0], d[1]));
    h2 p2b = __builtin_bit_cast(h2, __builtin_amdgcn_cvt_pkrtz(d[2], 1.0f));
    h2 r01 = __builtin_elementwise_max(p01, Z);
    h2 r2b = __builtin_elementwise_max(p2b, Z);   // [relu(d2), 1.0h bias]
    h2 t01 = __builtin_elementwise_min(p01, Z);
    h2 t2b = __builtin_elementwise_min(p2b, Z);   // [min(d2,0), 0]
    h2 e01 = __builtin_elementwise_exp2(t01);     // 2x v_exp_f16
    _Float16 e2 = __ocml_exp2_f16(t2b[0]);        // 1x v_exp_f16
    uint4v u;
    u[0] = __builtin_bit_cast(unsigned, r01);
    u[1] = __builtin_bit_cast(unsigned, r2b);
    u[2] = __builtin_bit_cast(unsigned, e01);
    u[3] = 0x3C000000u |                          // finite dead j7
           (unsigned)__builtin_bit_cast(unsigned short, e2);
    return __builtin_bit_cast(half8, u);
}

__device__ __forceinline__ float bperm(int byte_idx, float v) {
    return __builtin_bit_cast(float,
        __builtin_amdgcn_ds_bpermute(byte_idx, __builtin_bit_cast(int, v)));
}

// Wave-batched log-softmax + store for 4 tiles (dd[0..3] -> tiles gbase..+3).
__device__ __forceinline__ void softmax4(const float4v* dd, int gbase,
                                         int lane, int grp,
                                         float* __restrict__ out) {
    const float NLOG2E = -1.4426950408889634f;
    const float LN2f   = 0.6931471805599453f;
    const int bidx = (lane & 15) << 2;
    float a0 = bperm(bidx, dd[0][0]), a1 = bperm(bidx, dd[0][1]);
    float b0 = bperm(bidx, dd[1][0]), b1 = bperm(bidx, dd[1][1]);
    float c0 = bperm(bidx, dd[2][0]), c1 = bperm(bidx, dd[2][1]);
    float d0 = bperm(bidx, dd[3][0]), d1 = bperm(bidx, dd[3][1]);
    float l0 = (grp == 0) ? a0 : (grp == 1) ? b0 : (grp == 2) ? c0 : d0;
    float l1 = (grp == 0) ? a1 : (grp == 1) ? b1 : (grp == 2) ? c1 : d1;
    float mx  = fmaxf(l0, l1);
    float ad  = fabsf(l0 - l1);
    float e   = __builtin_amdgcn_exp2f(NLOG2E * ad);
    float lg  = __builtin_amdgcn_logf(1.0f + e);     // log2(1+e)
    float lse = fmaf(LN2f, lg, mx);
    ((float2*)out)[(gbase << 4) + lane] = make_float2(l0 - lse, l1 - lse);
}

__global__ __launch_bounds__(BLK, 4) void mlp_mfma(const float* __restrict__ x,
                                                   const _Float16* __restrict__ ws,
                                                   float* __restrict__ out) {
    const int lane  = threadIdx.x;        // single wave per block
    const int grp   = lane >> 4;
    const int col   = lane & 15;
    const int tile0 = blockIdx.x * TPW;   // < 131072, 32-bit safe

    const half8* wsv = (const half8*)ws;
    const unsigned g0_sel  = (grp == 0) ? 0xFFFFFFFFu : 0u;
    const unsigned bias_u1 = (grp == 3) ? 0x3C000000u : 0u;  // 1.0h @ j3 (k=27)
    const float4v ZV = {0.f, 0.f, 0.f, 0.f};

    // Load + pre-pack ALL 16 x fragments at wave start (1 VGPR each).
    unsigned xb[TPW];
    #pragma unroll
    for (int k = 0; k < TPW; ++k) {
        float2 xv = ((const float2*)x)[((tile0 + k) << 4) + col];
        xb[k] = __builtin_bit_cast(unsigned,
                    __builtin_amdgcn_cvt_pkrtz(xv.x, xv.y)) & g0_sel;
    }

    #pragma unroll
    for (int half = 0; half < 2; ++half) {
        half8 bf[8];
        #pragma unroll
        for (int k = 0; k < 8; ++k) {
            uint4v u;
            u[0] = xb[half * 8 + k];
            u[1] = bias_u1;
            u[2] = 0u; u[3] = 0u;
            bf[k] = __builtin_bit_cast(half8, u);
        }

        // 21-layer chain, 8 independent chains in flight.
        float4v dd[8];
        #pragma unroll
        for (int l = 0; l < NL; ++l) {
            half8 A = wsv[l * 64 + lane];
            #pragma unroll
            for (int k = 0; k < 8; ++k)
                dd[k] = __builtin_amdgcn_mfma_f32_16x16x32_f16(A, bf[k], ZV, 0, 0, 0);
            if (l < NL - 1) {
                #pragma unroll
                for (int k = 0; k < 8; ++k)
                    bf[k] = act_to_b(dd[k]);
            }
        }

        const int gb = tile0 + half * 8;
        softmax4(dd,     gb,     lane, grp, out);
        softmax4(dd + 4, gb + 4, lane, grp, out);
    }
}

extern "C" void kernel_launch(void* const* d_in, const int* in_sizes, int n_in,
                              void* d_out, int out_size, void* d_ws, size_t ws_size,
                              hipStream_t stream) {
    const float* x    = (const float*)d_in[0];
    const float* W1   = (const float*)d_in[1];
    const float* b1   = (const float*)d_in[2];
    const float* Wmid = (const float*)d_in[3];
    const float* bmid = (const float*)d_in[4];
    const float* W21  = (const float*)d_in[5];
    const float* b21  = (const float*)d_in[6];
    float* out = (float*)d_out;
    _Float16* ws = (_Float16*)d_ws;   // 21*512 halves = 21.5 KB

    build_frags<<<NL, 64, 0, stream>>>(W1, b1, Wmid, bmid, W21, b21, ws);

    const int nrows = in_sizes[0] / 2;           // 2097152
    const int tiles = nrows / 16;                // 131072
    const int blocks = tiles / TPW;              // 8192 single-wave blocks
    mlp_mfma<<<blocks, BLK, 0, stream>>>(x, ws, out);
}